// Round 11
// baseline (90.204 us; speedup 1.0000x reference)
//
#include <hip/hip_runtime.h>
#include <hip/hip_bf16.h>

#define D 256
#define TWOD 512
#define BM 128
#define BK 32

typedef __attribute__((ext_vector_type(8))) __bf16 bf16x8;
typedef __attribute__((ext_vector_type(4))) float f32x4;
typedef __attribute__((ext_vector_type(8))) unsigned short ushort8;

using as1_u32 = __attribute__((address_space(1))) const unsigned int;
using as3_u32 = __attribute__((address_space(3))) unsigned int;

__device__ __forceinline__ void gload_lds16(const void* g, void* l) {
    __builtin_amdgcn_global_load_lds((as1_u32*)g, (as3_u32*)l, 16, 0, 0);
}

// ---------- helpers ----------
__device__ __forceinline__ float bf2f(unsigned short u) {
    unsigned int x = ((unsigned int)u) << 16;
    return __uint_as_float(x);
}
__device__ __forceinline__ unsigned short f2bf_bits(float f) {
    unsigned int x = __float_as_uint(f);
    unsigned int r = (x + 0x7fffu + ((x >> 16) & 1u)) >> 16;  // RNE
    return (unsigned short)r;
}

// ---------- Kernel 0: w1 (fp32 [256][512]) -> WtP, fragment-packed bf16 ----------
// Packed so a wave's B-frag (c16 = jj/16, kblk = k/32) is 512 contiguous shorts:
//   WtP[(c16*8 + kblk)*512 + lane*8 + kj], lane = (jj&15) + 16*((k&31)>>3), kj = k&7
__global__ __launch_bounds__(256) void wt_conv_kernel(
    const float* __restrict__ w1, unsigned short* __restrict__ WtP)
{
    const int s = blockIdx.x * 256 + threadIdx.x;   // 0..131071
    const int o = s >> 9;        // w1 row (output unit)
    const int i = s & 511;       // w1 col (input dim)
    const float v = w1[s];
    const int jj = (i < D) ? o : (D + o);
    const int k  = (i < D) ? i : (i - D);
    const int c16 = jj >> 4, r = jj & 15;
    const int kblk = k >> 5, kin = k & 31;
    const int g = kin >> 3, kj = kin & 7;
    WtP[(size_t)((c16 * 8 + kblk) * 512 + (r + 16 * g) * 8 + kj)] = f2bf_bits(v);
}

// ---------- Kernel 1: MFMA node projection, counted-vmcnt pipeline ----------
// A: 3-buffer LDS (3x16KB), staged 2 K-steps ahead via global_load_lds.
// B: packed WtP (L2-resident), double-buffered in registers 1 step ahead.
// b1 folded into the A-half (cols < 256) at store time.
// XCD-pinned columns: all 4 col-blocks of a row-block on one XCD's L2.
__global__ __launch_bounds__(256, 3) void node_proj_mfma(
    const float* __restrict__ z, const unsigned short* __restrict__ WtP,
    const float* __restrict__ b1, unsigned short* __restrict__ C,
    int M, int Mblocks)
{
    __shared__ __align__(16) float Abuf[3][BM * BK];  // 3 x 16 KB

    const int bid    = blockIdx.x;
    const int rowblk = (bid >> 5) * 8 + (bid & 7);
    if (rowblk >= Mblocks) return;                 // block-uniform
    const int m0 = rowblk * BM;
    const int cb = ((bid >> 3) & 3) * BM;

    const int t    = threadIdx.x;
    const int lane = t & 63;
    const int w    = t >> 6;

    const int r16 = lane & 15;
    const int g   = lane >> 4;       // 0..3

    const int wm = (w >> 1) * 64;    // wave row offset within tile
    const int wn = (w & 1) * 64;     // wave col offset within tile
    const int c16b = (cb + wn) >> 4;

    f32x4 acc[4][4];
    #pragma unroll
    for (int mt = 0; mt < 4; ++mt)
        #pragma unroll
        for (int nt = 0; nt < 4; ++nt)
            acc[mt][nt] = (f32x4){0.f, 0.f, 0.f, 0.f};

    auto stageA = [&](int buf, int k0) {
        // A tile: 128x32 f32 = 1024 16B-chunks, 4 per thread (4 VMEM/wave).
        // LDS chunk c = r*8+q holds global col-chunk q^(r&7) of row r.
        #pragma unroll
        for (int i = 0; i < 4; ++i) {
            const int c = i * 256 + t;
            const int r = c >> 3;
            const int q = c & 7;
            const int col = ((q ^ (r & 7)) << 2);
            const int row = min(m0 + r, M - 1);      // clamp: last-block tail
            const float* gsrc = z + (size_t)row * D + k0 + col;
            float* ldst = &Abuf[buf][(size_t)(i * 256 + w * 64) * 4]; // wave-uniform base
            gload_lds16(gsrc, ldst);
        }
    };

    bf16x8 bb[2][4];
    auto loadB = [&](int par, int kt) {
        #pragma unroll
        for (int nt = 0; nt < 4; ++nt) {
            const ushort8 bu = *(const ushort8*)(
                WtP + (size_t)(((c16b + nt) * 8 + kt) * 512 + lane * 8));
            bb[par][nt] = __builtin_bit_cast(bf16x8, bu);
        }
    };

    // Prologue: A(0), A(1) staged; B(0) in regs. Outstanding after: 12.
    stageA(0, 0);
    stageA(1, BK);
    __builtin_amdgcn_sched_barrier(0);
    loadB(0, 0);

    #pragma unroll
    for (int kt = 0; kt < 8; ++kt) {
        // Secure stage(kt); leave stage(kt+1) (+ newer B-loads) in flight.
        if (kt == 0 || kt == 7) asm volatile("s_waitcnt vmcnt(8)" ::: "memory");
        else                    asm volatile("s_waitcnt vmcnt(12)" ::: "memory");
        __builtin_amdgcn_s_barrier();   // waves past here have retired ds_reads of buf (kt+2)%3

        if (kt < 6) stageA((kt + 2) % 3, (kt + 2) * BK);
        __builtin_amdgcn_sched_barrier(0);   // pin: A-stages precede B-loads
        if (kt < 7) loadB((kt + 1) & 1, kt + 1);

        // A fragments (fp32 -> bf16 in-register, swizzled LDS read)
        bf16x8 a[4];
        #pragma unroll
        for (int mt = 0; mt < 4; ++mt) {
            const int rl = wm + mt * 16 + r16;
            const int sw = rl & 7;
            const f32x4 f0 = *(const f32x4*)&Abuf[kt % 3][rl * 32 + (((2 * g) ^ sw) << 2)];
            const f32x4 f1 = *(const f32x4*)&Abuf[kt % 3][rl * 32 + (((2 * g + 1) ^ sw) << 2)];
            bf16x8 tt;
            tt[0] = (__bf16)f0[0]; tt[1] = (__bf16)f0[1];
            tt[2] = (__bf16)f0[2]; tt[3] = (__bf16)f0[3];
            tt[4] = (__bf16)f1[0]; tt[5] = (__bf16)f1[1];
            tt[6] = (__bf16)f1[2]; tt[7] = (__bf16)f1[3];
            a[mt] = tt;
        }

        __builtin_amdgcn_s_setprio(1);
        #pragma unroll
        for (int nt = 0; nt < 4; ++nt)
            #pragma unroll
            for (int mt = 0; mt < 4; ++mt)
                acc[mt][nt] = __builtin_amdgcn_mfma_f32_16x16x32_bf16(
                    bb[kt & 1][nt], a[mt], acc[mt][nt], 0, 0, 0);
        __builtin_amdgcn_s_setprio(0);
    }

    // Store: lane holds 4 consecutive C-columns for one row. Fold b1 into A-half.
    #pragma unroll
    for (int mt = 0; mt < 4; ++mt) {
        const int row = m0 + wm + mt * 16 + r16;
        if (row < M) {
            #pragma unroll
            for (int nt = 0; nt < 4; ++nt) {
                const int col = cb + wn + nt * 16 + g * 4;
                f32x4 av = acc[mt][nt];
                if (col < D) {   // block/nt-uniform branch
                    const float4 bv = *(const float4*)(b1 + col);
                    av[0] += bv.x; av[1] += bv.y; av[2] += bv.z; av[3] += bv.w;
                }
                ushort4 pk;
                pk.x = f2bf_bits(av[0]);
                pk.y = f2bf_bits(av[1]);
                pk.z = f2bf_bits(av[2]);
                pk.w = f2bf_bits(av[3]);
                *(ushort4*)(C + (size_t)row * TWOD + col) = pk;
            }
        }
    }
}

// ---------- Kernel 2: per-edge relu-dot, 8 edges per half-wave (one-shot) ----------
// out[e] = sum_j relu(Ca[u,j] + Cb[v,j]) * w2[j] + b2   (b1 already in Ca)
__global__ __launch_bounds__(256) void edge_kernel(
    const int* __restrict__ ei, const unsigned short* __restrict__ C,
    const float* __restrict__ w2, const float* __restrict__ b2,
    float* __restrict__ out, int E)
{
    const int h   = threadIdx.x & 31;
    const int gid = (blockIdx.x * blockDim.x + threadIdx.x) >> 5;   // half-wave id
    const int j0  = h * 8;
    const int e0  = gid * 8;
    if (e0 >= E) return;

    const float4 w2a = *(const float4*)(w2 + j0);
    const float4 w2b = *(const float4*)(w2 + j0 + 4);
    const float  b2s = b2[0];

    // indices (lane-uniform per half-wave; broadcast loads)
    int u[8], v[8];
    #pragma unroll
    for (int i = 0; i < 8; ++i) {
        const int e = min(e0 + i, E - 1);
        u[i] = ei[e];
        v[i] = ei[E + e];
    }

    // 16 independent gathers in flight
    ushort8 ua[8], ub[8];
    #pragma unroll
    for (int i = 0; i < 8; ++i) {
        ua[i] = *(const ushort8*)(C + (size_t)u[i] * TWOD + j0);
        ub[i] = *(const ushort8*)(C + (size_t)v[i] * TWOD + D + j0);
    }

    float s[8];
    #pragma unroll
    for (int i = 0; i < 8; ++i) {
        float acc = 0.f;
        acc += fmaxf(bf2f(ua[i][0]) + bf2f(ub[i][0]), 0.f) * w2a.x;
        acc += fmaxf(bf2f(ua[i][1]) + bf2f(ub[i][1]), 0.f) * w2a.y;
        acc += fmaxf(bf2f(ua[i][2]) + bf2f(ub[i][2]), 0.f) * w2a.z;
        acc += fmaxf(bf2f(ua[i][3]) + bf2f(ub[i][3]), 0.f) * w2a.w;
        acc += fmaxf(bf2f(ua[i][4]) + bf2f(ub[i][4]), 0.f) * w2b.x;
        acc += fmaxf(bf2f(ua[i][5]) + bf2f(ub[i][5]), 0.f) * w2b.y;
        acc += fmaxf(bf2f(ua[i][6]) + bf2f(ub[i][6]), 0.f) * w2b.z;
        acc += fmaxf(bf2f(ua[i][7]) + bf2f(ub[i][7]), 0.f) * w2b.w;
        s[i] = acc;
    }

    #pragma unroll
    for (int off = 16; off; off >>= 1) {
        #pragma unroll
        for (int i = 0; i < 8; ++i)
            s[i] += __shfl_xor(s[i], off);
    }

    if (h == 0) {
        #pragma unroll
        for (int i = 0; i < 8; ++i)
            if (e0 + i < E) out[e0 + i] = s[i] + b2s;
    }
}

extern "C" void kernel_launch(void* const* d_in, const int* in_sizes, int n_in,
                              void* d_out, int out_size, void* d_ws, size_t ws_size,
                              hipStream_t stream) {
    const float* z  = (const float*)d_in[0];
    const int*   ei = (const int*)d_in[1];
    const float* w1 = (const float*)d_in[2];
    const float* b1 = (const float*)d_in[3];
    const float* w2 = (const float*)d_in[4];
    const float* b2 = (const float*)d_in[5];
    float* out = (float*)d_out;

    const int M = in_sizes[0] / D;   // 50000 nodes
    const int E = in_sizes[1] / 2;   // 320000 edges

    unsigned short* C   = (unsigned short*)d_ws;   // M*512 bf16 = 51.2 MB
    unsigned short* WtP = (unsigned short*)d_out;  // 256 KB scratch inside d_out;
                                                   // consumed by GEMM, then overwritten

    wt_conv_kernel<<<512, 256, 0, stream>>>(w1, WtP);

    const int Mblocks = (M + BM - 1) / BM;                 // 391
    const int stripes = (Mblocks + 7) / 8;                 // 49
    node_proj_mfma<<<stripes * 32, 256, 0, stream>>>(z, WtP, b1, C, M, Mblocks);

    const int hw = (E + 7) / 8;                            // half-waves
    edge_kernel<<<(hw + 7) / 8, 256, 0, stream>>>(ei, C, w2, b2, out, E);
}

// Round 12
// 86.800 us; speedup vs baseline: 1.0392x; 1.0392x over previous
//
#include <hip/hip_runtime.h>
#include <hip/hip_bf16.h>

#define D 256
#define TWOD 512
#define BM 128
#define BK 32

typedef __attribute__((ext_vector_type(8))) __bf16 bf16x8;
typedef __attribute__((ext_vector_type(4))) float f32x4;
typedef __attribute__((ext_vector_type(8))) unsigned short ushort8;

using as1_u32 = __attribute__((address_space(1))) const unsigned int;
using as3_u32 = __attribute__((address_space(3))) unsigned int;

__device__ __forceinline__ void gload_lds16(const void* g, void* l) {
    __builtin_amdgcn_global_load_lds((as1_u32*)g, (as3_u32*)l, 16, 0, 0);
}

// ---------- helpers ----------
__device__ __forceinline__ float bf2f(unsigned short u) {
    unsigned int x = ((unsigned int)u) << 16;
    return __uint_as_float(x);
}
__device__ __forceinline__ unsigned short f2bf_bits(float f) {
    unsigned int x = __float_as_uint(f);
    unsigned int r = (x + 0x7fffu + ((x >> 16) & 1u)) >> 16;  // RNE
    return (unsigned short)r;
}

// ---------- Kernel 0: w1 (fp32 [256][512]) -> WtP, fragment-packed bf16 ----------
// Packed so a wave's B-frag (c16 = jj/16, kblk = k/32) is 512 contiguous shorts:
//   WtP[(c16*8 + kblk)*512 + lane*8 + kj], lane = (jj&15) + 16*((k&31)>>3), kj = k&7
__global__ __launch_bounds__(256) void wt_conv_kernel(
    const float* __restrict__ w1, unsigned short* __restrict__ WtP)
{
    const int s = blockIdx.x * 256 + threadIdx.x;   // 0..131071
    const int o = s >> 9;        // w1 row (output unit)
    const int i = s & 511;       // w1 col (input dim)
    const float v = w1[s];
    const int jj = (i < D) ? o : (D + o);
    const int k  = (i < D) ? i : (i - D);
    const int c16 = jj >> 4, r = jj & 15;
    const int kblk = k >> 5, kin = k & 31;
    const int g = kin >> 3, kj = kin & 7;
    WtP[(size_t)((c16 * 8 + kblk) * 512 + (r + 16 * g) * 8 + kj)] = f2bf_bits(v);
}

// ---------- Kernel 1: MFMA node projection, counted-vmcnt pipeline ----------
// (exact round-10 structure — measured ~37 us; do not perturb)
// A: 3-buffer LDS (3x16KB), staged 2 K-steps ahead via global_load_lds.
// B: packed WtP (L2-resident), double-buffered in registers 1 step ahead.
// XCD-pinned columns: all 4 col-blocks of a row-block on one XCD's L2.
__global__ __launch_bounds__(256, 3) void node_proj_mfma(
    const float* __restrict__ z, const unsigned short* __restrict__ WtP,
    unsigned short* __restrict__ C, int M, int Mblocks)
{
    __shared__ __align__(16) float Abuf[3][BM * BK];  // 3 x 16 KB

    const int bid    = blockIdx.x;
    const int rowblk = (bid >> 5) * 8 + (bid & 7);
    if (rowblk >= Mblocks) return;                 // block-uniform
    const int m0 = rowblk * BM;
    const int cb = ((bid >> 3) & 3) * BM;

    const int t    = threadIdx.x;
    const int lane = t & 63;
    const int w    = t >> 6;

    const int r16 = lane & 15;
    const int g   = lane >> 4;       // 0..3

    const int wm = (w >> 1) * 64;    // wave row offset within tile
    const int wn = (w & 1) * 64;     // wave col offset within tile
    const int c16b = (cb + wn) >> 4;

    f32x4 acc[4][4];
    #pragma unroll
    for (int mt = 0; mt < 4; ++mt)
        #pragma unroll
        for (int nt = 0; nt < 4; ++nt)
            acc[mt][nt] = (f32x4){0.f, 0.f, 0.f, 0.f};

    auto stageA = [&](int buf, int k0) {
        // A tile: 128x32 f32 = 1024 16B-chunks, 4 per thread (4 VMEM/wave).
        // LDS chunk c = r*8+q holds global col-chunk q^(r&7) of row r.
        #pragma unroll
        for (int i = 0; i < 4; ++i) {
            const int c = i * 256 + t;
            const int r = c >> 3;
            const int q = c & 7;
            const int col = ((q ^ (r & 7)) << 2);
            const int row = min(m0 + r, M - 1);      // clamp: last-block tail
            const float* gsrc = z + (size_t)row * D + k0 + col;
            float* ldst = &Abuf[buf][(size_t)(i * 256 + w * 64) * 4]; // wave-uniform base
            gload_lds16(gsrc, ldst);
        }
    };

    bf16x8 bb[2][4];
    auto loadB = [&](int par, int kt) {
        #pragma unroll
        for (int nt = 0; nt < 4; ++nt) {
            const ushort8 bu = *(const ushort8*)(
                WtP + (size_t)(((c16b + nt) * 8 + kt) * 512 + lane * 8));
            bb[par][nt] = __builtin_bit_cast(bf16x8, bu);
        }
    };

    // Prologue: A(0), A(1) staged; B(0) in regs. Outstanding after: 12.
    stageA(0, 0);
    stageA(1, BK);
    __builtin_amdgcn_sched_barrier(0);
    loadB(0, 0);

    #pragma unroll
    for (int kt = 0; kt < 8; ++kt) {
        // Secure stage(kt); leave stage(kt+1) (+ newer B-loads) in flight.
        if (kt == 0 || kt == 7) asm volatile("s_waitcnt vmcnt(8)" ::: "memory");
        else                    asm volatile("s_waitcnt vmcnt(12)" ::: "memory");
        __builtin_amdgcn_s_barrier();   // waves past here have retired ds_reads of buf (kt+2)%3

        if (kt < 6) stageA((kt + 2) % 3, (kt + 2) * BK);
        __builtin_amdgcn_sched_barrier(0);   // pin: A-stages precede B-loads
        if (kt < 7) loadB((kt + 1) & 1, kt + 1);

        // A fragments (fp32 -> bf16 in-register, swizzled LDS read)
        bf16x8 a[4];
        #pragma unroll
        for (int mt = 0; mt < 4; ++mt) {
            const int rl = wm + mt * 16 + r16;
            const int sw = rl & 7;
            const f32x4 f0 = *(const f32x4*)&Abuf[kt % 3][rl * 32 + (((2 * g) ^ sw) << 2)];
            const f32x4 f1 = *(const f32x4*)&Abuf[kt % 3][rl * 32 + (((2 * g + 1) ^ sw) << 2)];
            bf16x8 tt;
            tt[0] = (__bf16)f0[0]; tt[1] = (__bf16)f0[1];
            tt[2] = (__bf16)f0[2]; tt[3] = (__bf16)f0[3];
            tt[4] = (__bf16)f1[0]; tt[5] = (__bf16)f1[1];
            tt[6] = (__bf16)f1[2]; tt[7] = (__bf16)f1[3];
            a[mt] = tt;
        }

        __builtin_amdgcn_s_setprio(1);
        #pragma unroll
        for (int nt = 0; nt < 4; ++nt)
            #pragma unroll
            for (int mt = 0; mt < 4; ++mt)
                acc[mt][nt] = __builtin_amdgcn_mfma_f32_16x16x32_bf16(
                    bb[kt & 1][nt], a[mt], acc[mt][nt], 0, 0, 0);
        __builtin_amdgcn_s_setprio(0);
    }

    // Store: lane holds 4 consecutive C-columns for one row.
    #pragma unroll
    for (int mt = 0; mt < 4; ++mt) {
        const int row = m0 + wm + mt * 16 + r16;
        if (row < M) {
            #pragma unroll
            for (int nt = 0; nt < 4; ++nt) {
                const int col = cb + wn + nt * 16 + g * 4;
                ushort4 pk;
                pk.x = f2bf_bits(acc[mt][nt][0]);
                pk.y = f2bf_bits(acc[mt][nt][1]);
                pk.z = f2bf_bits(acc[mt][nt][2]);
                pk.w = f2bf_bits(acc[mt][nt][3]);
                *(ushort4*)(C + (size_t)row * TWOD + col) = pk;
            }
        }
    }
}

// ---------- Kernel 2: per-edge relu-dot, 8 edges per half-wave (one-shot) ----------
// out[e] = sum_j relu(Ca[u,j] + Cb[v,j] + b1[j]) * w2[j] + b2
__global__ __launch_bounds__(256) void edge_kernel(
    const int* __restrict__ ei, const unsigned short* __restrict__ C,
    const float* __restrict__ b1, const float* __restrict__ w2,
    const float* __restrict__ b2, float* __restrict__ out, int E)
{
    const int h   = threadIdx.x & 31;
    const int gid = (blockIdx.x * blockDim.x + threadIdx.x) >> 5;   // half-wave id
    const int j0  = h * 8;
    const int e0  = gid * 8;
    if (e0 >= E) return;

    const float4 w2a = *(const float4*)(w2 + j0);
    const float4 w2b = *(const float4*)(w2 + j0 + 4);
    const float4 b1a = *(const float4*)(b1 + j0);
    const float4 b1b = *(const float4*)(b1 + j0 + 4);
    const float  b2s = b2[0];

    // indices: vectorized when a full 8-pack is in range (e0 is 8-aligned)
    int u[8], v[8];
    if (e0 + 8 <= E) {
        const int4 ua4 = *(const int4*)(ei + e0);
        const int4 ub4 = *(const int4*)(ei + e0 + 4);
        const int4 va4 = *(const int4*)(ei + E + e0);
        const int4 vb4 = *(const int4*)(ei + E + e0 + 4);
        u[0] = ua4.x; u[1] = ua4.y; u[2] = ua4.z; u[3] = ua4.w;
        u[4] = ub4.x; u[5] = ub4.y; u[6] = ub4.z; u[7] = ub4.w;
        v[0] = va4.x; v[1] = va4.y; v[2] = va4.z; v[3] = va4.w;
        v[4] = vb4.x; v[5] = vb4.y; v[6] = vb4.z; v[7] = vb4.w;
    } else {
        #pragma unroll
        for (int i = 0; i < 8; ++i) {
            const int e = min(e0 + i, E - 1);
            u[i] = ei[e];
            v[i] = ei[E + e];
        }
    }

    // 16 independent gathers in flight
    ushort8 ua[8], ub[8];
    #pragma unroll
    for (int i = 0; i < 8; ++i) {
        ua[i] = *(const ushort8*)(C + (size_t)u[i] * TWOD + j0);
        ub[i] = *(const ushort8*)(C + (size_t)v[i] * TWOD + D + j0);
    }

    float s[8];
    #pragma unroll
    for (int i = 0; i < 8; ++i) {
        float acc = 0.f;
        acc += fmaxf(bf2f(ua[i][0]) + bf2f(ub[i][0]) + b1a.x, 0.f) * w2a.x;
        acc += fmaxf(bf2f(ua[i][1]) + bf2f(ub[i][1]) + b1a.y, 0.f) * w2a.y;
        acc += fmaxf(bf2f(ua[i][2]) + bf2f(ub[i][2]) + b1a.z, 0.f) * w2a.z;
        acc += fmaxf(bf2f(ua[i][3]) + bf2f(ub[i][3]) + b1a.w, 0.f) * w2a.w;
        acc += fmaxf(bf2f(ua[i][4]) + bf2f(ub[i][4]) + b1b.x, 0.f) * w2b.x;
        acc += fmaxf(bf2f(ua[i][5]) + bf2f(ub[i][5]) + b1b.y, 0.f) * w2b.y;
        acc += fmaxf(bf2f(ua[i][6]) + bf2f(ub[i][6]) + b1b.z, 0.f) * w2b.z;
        acc += fmaxf(bf2f(ua[i][7]) + bf2f(ub[i][7]) + b1b.w, 0.f) * w2b.w;
        s[i] = acc;
    }

    #pragma unroll
    for (int off = 16; off; off >>= 1) {
        #pragma unroll
        for (int i = 0; i < 8; ++i)
            s[i] += __shfl_xor(s[i], off);
    }

    if (h == 0) {
        #pragma unroll
        for (int i = 0; i < 8; ++i)
            if (e0 + i < E) out[e0 + i] = s[i] + b2s;
    }
}

extern "C" void kernel_launch(void* const* d_in, const int* in_sizes, int n_in,
                              void* d_out, int out_size, void* d_ws, size_t ws_size,
                              hipStream_t stream) {
    const float* z  = (const float*)d_in[0];
    const int*   ei = (const int*)d_in[1];
    const float* w1 = (const float*)d_in[2];
    const float* b1 = (const float*)d_in[3];
    const float* w2 = (const float*)d_in[4];
    const float* b2 = (const float*)d_in[5];
    float* out = (float*)d_out;

    const int M = in_sizes[0] / D;   // 50000 nodes
    const int E = in_sizes[1] / 2;   // 320000 edges

    unsigned short* C   = (unsigned short*)d_ws;   // M*512 bf16 = 51.2 MB
    unsigned short* WtP = (unsigned short*)d_out;  // 256 KB scratch inside d_out;
                                                   // consumed by GEMM, then overwritten

    wt_conv_kernel<<<512, 256, 0, stream>>>(w1, WtP);

    const int Mblocks = (M + BM - 1) / BM;                 // 391
    const int stripes = (Mblocks + 7) / 8;                 // 49
    node_proj_mfma<<<stripes * 32, 256, 0, stream>>>(z, WtP, C, M, Mblocks);

    const int hw = (E + 7) / 8;                            // half-waves (8 edges each)
    edge_kernel<<<(hw + 7) / 8, 256, 0, stream>>>(ei, C, b1, w2, b2, out, E);
}